// Round 5
// baseline (961.318 us; speedup 1.0000x reference)
//
#include <hip/hip_runtime.h>
#include <hip/hip_bf16.h>

using u16   = unsigned short;
using u16x4 = __attribute__((ext_vector_type(4))) unsigned short;
using u16x8 = __attribute__((ext_vector_type(8))) unsigned short;
using s16x8 = __attribute__((ext_vector_type(8))) short;
using f32x4 = __attribute__((ext_vector_type(4))) float;

#define KPAD 136   // bf16 pad stride: 272B rows = 17x16B -> aligned b128, 2-way banks
#define XP   136
#define OP   264
#define EB   64

// raw barrier: LDS-visibility only, does NOT drain vmcnt -> prefetch loads stay in flight
#define BARRIER() asm volatile("s_waitcnt lgkmcnt(0)\n\ts_barrier" ::: "memory")

__device__ __forceinline__ float bf2f(u16 u){
  unsigned int x = ((unsigned int)u) << 16;
  float f; __builtin_memcpy(&f, &x, 4); return f;
}
__device__ __forceinline__ u16 f2bf(float f){
  __hip_bfloat16 h = __float2bfloat16(f);
  u16 u; __builtin_memcpy(&u, &h, 2); return u;
}
__device__ __forceinline__ f32x4 mfma16(s16x8 a, s16x8 b, f32x4 c){
  return __builtin_amdgcn_mfma_f32_16x16x32_bf16(a, b, c, 0, 0, 0);
}

// ---------------------------------------------------------------------------
// prep: WF  = layer-1 hi/lo fragment buffer [h=2][nb=16][ks=4][pair=2][lane=64][8]
//       WF2 = W2 bf16 fragment buffer [nb=8][ks=4][lane=64][8]
//       params: w1t(128) | wrt(128) | Wo(128) | biasC(256)
// ---------------------------------------------------------------------------
__global__ __launch_bounds__(256) void prep_kernel(
    const float* __restrict__ W1, const float* __restrict__ W2,
    const float* __restrict__ Wo, const float* __restrict__ Wr,
    const float* __restrict__ b1, const float* __restrict__ b2,
    const float* __restrict__ br,
    u16* __restrict__ WF, u16* __restrict__ WF2, float* __restrict__ params)
{
  const int tid = blockIdx.x*256 + threadIdx.x;
  const int nth = gridDim.x*256;
  for (int id = tid; id < 131072; id += nth){
    const int j    = id & 7;
    const int lane = (id >> 3) & 63;
    const int pair = (id >> 9) & 1;
    const int ks   = (id >> 10) & 3;
    const int nb   = (id >> 12) & 15;
    const int h    = (id >> 16) & 1;
    const int k = ks*32 + (lane >> 4)*8 + j;
    const int n = nb*16 + (lane & 15);
    const float v = ((n < 128) ? W1 : Wr)[(h*128 + k)*128 + (n & 127)];
    const u16 hi = f2bf(v);
    WF[id] = pair ? f2bf(v - bf2f(hi)) : hi;
  }
  for (int id = tid; id < 16384; id += nth){
    const int j    = id & 7;
    const int lane = (id >> 3) & 63;
    const int ks   = (id >> 9) & 3;
    const int nb   = (id >> 11) & 7;
    const int k = ks*32 + (lane >> 4)*8 + j;
    const int n = nb*16 + (lane & 15);
    WF2[id] = f2bf(W2[k*128 + n]);
  }
  for (int id = tid; id < 128; id += nth){
    params[id]       = W1[256*128 + id];      // w1t
    params[128 + id] = Wr[256*128 + id];      // wrt
    params[256 + id] = Wo[id];                // Wo
    params[384 + id]       = b1[id];          // biasC 0..127
    params[384 + 128 + id] = br[id] + b2[id]; // biasC 128..255
  }
}

// ---------------------------------------------------------------------------
// mm: out[row][0..255] = emb[row] @ Wcat (+bias), split-bf16 3-MFMA.
// 512 thr = 8 waves, 64-row tiles, W frags register-stationary (wave w owns
// cols w*16 and (w+8)*16). LDS 34.8KB -> 4 blocks/CU. Linear global access.
// ---------------------------------------------------------------------------
__global__ __launch_bounds__(512, 8) void mm_kernel(
    const float* __restrict__ emb, int nrows, int ntiles,
    const u16* __restrict__ WFh, const float* __restrict__ bias,
    u16* __restrict__ outbuf)
{
  __shared__ __align__(16) char smem_raw[64*XP*2*2];   // 34816 B
  u16* xhi = (u16*)smem_raw;              // [64][XP]
  u16* xlo = xhi + 64*XP;
  u16* sO  = (u16*)smem_raw;              // aliased after compute: [64][OP]
  const int t = threadIdx.x;
  const int l = t & 63, w = t >> 6;       // w in [0,8)
  const int lrow = l & 15, lq = l >> 4;
  s16x8 wf[2][4][2];                      // [nbh][ks][hi/lo]
#pragma unroll
  for (int nbh = 0; nbh < 2; ++nbh)
#pragma unroll
    for (int ks = 0; ks < 4; ++ks){
      const int nb = w + nbh*8;
      const u16* base = WFh + (size_t)((nb*4 + ks)*2)*512 + l*8;
      wf[nbh][ks][0] = *(const s16x8*)(base);
      wf[nbh][ks][1] = *(const s16x8*)(base + 512);
    }
  float bv[2][4] = {{0.f,0.f,0.f,0.f},{0.f,0.f,0.f,0.f}};
  if (bias){
#pragma unroll
    for (int nbh = 0; nbh < 2; ++nbh)
#pragma unroll
      for (int r = 0; r < 4; ++r)
        bv[nbh][r] = bias[(w + nbh*8)*16 + lq*4 + r];
  }
  for (int tile = blockIdx.x; tile < ntiles; tile += gridDim.x){
    const int row0 = tile*64;
    BARRIER();   // prev tile's sO fully consumed
#pragma unroll
    for (int i = 0; i < 4; ++i){
      const int f4 = i*512 + t;
      const int r = f4 >> 5, kc = f4 & 31;
      int grow = row0 + r; if (grow >= nrows) grow = nrows - 1;
      const float4 v = *(const float4*)(emb + (size_t)grow*128 + kc*4);
      const float vv[4] = {v.x, v.y, v.z, v.w};
      u16x4 h4, l4;
#pragma unroll
      for (int q = 0; q < 4; ++q){
        const u16 hi = f2bf(vv[q]);
        h4[q] = hi;
        l4[q] = f2bf(vv[q] - bf2f(hi));
      }
      *(u16x4*)(xhi + r*XP + kc*4) = h4;
      *(u16x4*)(xlo + r*XP + kc*4) = l4;
    }
    BARRIER();
    f32x4 acc[2][4];                      // [nbh][mb]
#pragma unroll
    for (int a = 0; a < 2; ++a)
#pragma unroll
      for (int b = 0; b < 4; ++b) acc[a][b] = (f32x4){0.f,0.f,0.f,0.f};
#pragma unroll
    for (int mb = 0; mb < 4; ++mb){
      const int mro = (mb*16 + lrow)*XP + lq*8;
#pragma unroll
      for (int ks = 0; ks < 4; ++ks){
        const s16x8 xh = *(const s16x8*)(xhi + mro + ks*32);
        const s16x8 xl = *(const s16x8*)(xlo + mro + ks*32);
#pragma unroll
        for (int nbh = 0; nbh < 2; ++nbh){
          acc[nbh][mb] = mfma16(wf[nbh][ks][0], xh, acc[nbh][mb]);
          acc[nbh][mb] = mfma16(wf[nbh][ks][1], xh, acc[nbh][mb]);
          acc[nbh][mb] = mfma16(wf[nbh][ks][0], xl, acc[nbh][mb]);
        }
      }
    }
    BARRIER();   // x consumed -> alias LDS as sO
#pragma unroll
    for (int nbh = 0; nbh < 2; ++nbh)
#pragma unroll
      for (int mb = 0; mb < 4; ++mb){
        const int m = mb*16 + lrow;
        u16x4 o;
#pragma unroll
        for (int r = 0; r < 4; ++r) o[r] = f2bf(acc[nbh][mb][r] + bv[nbh][r]);
        *(u16x4*)(sO + m*OP + (w + nbh*8)*16 + lq*4) = o;
      }
    BARRIER();
#pragma unroll
    for (int i = 0; i < 4; ++i){
      const int idx = i*512 + t;
      const int m = idx >> 5, c = idx & 31;
      const int grow = row0 + m;
      if (grow < nrows){
        const u16x8 v = *(const u16x8*)(sO + m*OP + c*8);
        *(u16x8*)(outbuf + (size_t)grow*256 + c*8) = v;
      }
    }
  }
}

// ---------------------------------------------------------------------------
// Edge kernel: 512 thr (8 waves), 64 edges/tile, LDS 35.8KB -> 4 blocks/CU.
// W2 frags in registers. Software pipeline: next-tile indices issued before
// barrier, next-tile gathers issued right after LDS writes; raw s_barrier
// (lgkmcnt only) keeps them in flight under MFMA+epilogue.
// Swapped-operand MFMA: D = [out-col][edge] -> lane-local vectorized epilogue.
// ---------------------------------------------------------------------------
__global__ __launch_bounds__(512, 8) void edge_kernel(
    const int* __restrict__ ei, const float* __restrict__ tte,
    const u16* __restrict__ PP, const u16* __restrict__ CC,
    const u16* __restrict__ WF2, const float* __restrict__ params,
    const float* __restrict__ bo_p, float* __restrict__ out, int E, int ntiles)
{
  __shared__ u16 sA[EB*KPAD];      // h1  bf16 [64][136]
  __shared__ u16 sR[EB*KPAD];      // res bf16 [64][136]
  __shared__ float souts[4][EB];
  const int t = threadIdx.x;
  const int l = t & 63, w = t >> 6;
  const int lrow = l & 15, lk = l >> 4;
  const int rh = w & 1, ch = w >> 1;     // edge-half(32), col-quarter(32)
  const int gid = t >> 5, gl = t & 31;   // gather group / chunk
  const float bo = bo_p[0];
  // W2 fragments for this wave's 32 cols
  s16x8 wf2[2][4];
#pragma unroll
  for (int nb = 0; nb < 2; ++nb)
#pragma unroll
    for (int ks = 0; ks < 4; ++ks)
      wf2[nb][ks] = *(const s16x8*)(WF2 + (size_t)(((ch*2 + nb)*4 + ks)*64 + l)*8);
  // per-thread layer-1 tte-row slice (fixed chunk gl) and Wo slices
  float wt[8];
  {
    const float* base = params + ((gl < 16) ? 0 : 128) + (gl & 15)*8;
#pragma unroll
    for (int q = 0; q < 8; ++q) wt[q] = base[q];
  }
  float wo[2][4];
#pragma unroll
  for (int nb = 0; nb < 2; ++nb){
    const float4 v = *(const float4*)(params + 256 + ch*32 + nb*16 + lk*4);
    wo[nb][0] = v.x; wo[nb][1] = v.y; wo[nb][2] = v.z; wo[nb][3] = v.w;
  }

  int tile = blockIdx.x;
  if (tile >= ntiles) return;
  // prologue: indices + gathers for first tile
  float ctt[4];
  u16x8 cpv[4], ccv[4];
  {
    int cs[4], cd[4];
#pragma unroll
    for (int i = 0; i < 4; ++i){
      int e = tile*EB + i*16 + gid; if (e >= E) e = E - 1;
      cs[i] = ei[e]; cd[i] = ei[E + e]; ctt[i] = tte[e];
    }
#pragma unroll
    for (int i = 0; i < 4; ++i){
      cpv[i] = *(const u16x8*)(PP + (size_t)cs[i]*256 + gl*8);
      ccv[i] = *(const u16x8*)(CC + (size_t)cd[i]*256 + gl*8);
    }
  }

  for (; tile < ntiles; tile += gridDim.x){
    const int ntile = tile + gridDim.x;
    // [A] next-tile indices (clamped; wasted on last iter only)
    int nxs[4], nxd[4]; float ntt[4];
#pragma unroll
    for (int i = 0; i < 4; ++i){
      int e = ntile*EB + i*16 + gid; if (e >= E) e = E - 1;
      nxs[i] = ei[e]; nxd[i] = ei[E + e]; ntt[i] = tte[e];
    }
    // [B] prev compute done (sA/sR free)
    BARRIER();
    // [C] convert current gathers -> sA/sR
#pragma unroll
    for (int i = 0; i < 4; ++i){
      const int e = i*16 + gid;
      const int jj = (gl & 15)*8;
      const float tt = ctt[i];
      u16x8 o;
#pragma unroll
      for (int q = 0; q < 8; ++q){
        float v = bf2f(cpv[i][q]) + bf2f(ccv[i][q]) + tt * wt[q];
        if (gl < 16) v = fmaxf(v, 0.f);
        o[q] = f2bf(v);
      }
      u16* dst = (gl < 16) ? (sA + e*KPAD + jj) : (sR + e*KPAD + jj);
      *(u16x8*)dst = o;
    }
    // [D] next-tile gathers -- stay in flight across the raw barrier
    u16x8 npv[4], ncv[4];
#pragma unroll
    for (int i = 0; i < 4; ++i){
      npv[i] = *(const u16x8*)(PP + (size_t)nxs[i]*256 + gl*8);
      ncv[i] = *(const u16x8*)(CC + (size_t)nxd[i]*256 + gl*8);
    }
    // [E] sA/sR visible
    BARRIER();
    // [F] MFMA: acc[nb][mb], D row=out-col(lk*4+r), D col=edge(lrow)
    f32x4 acc[2][2];
#pragma unroll
    for (int a = 0; a < 2; ++a)
#pragma unroll
      for (int b = 0; b < 2; ++b) acc[a][b] = (f32x4){0.f,0.f,0.f,0.f};
#pragma unroll
    for (int ks = 0; ks < 4; ++ks){
      const int koff = ks*32 + lk*8;
      const s16x8 h0 = *(const s16x8*)(sA + (rh*32 + lrow)*KPAD + koff);
      const s16x8 h1 = *(const s16x8*)(sA + (rh*32 + 16 + lrow)*KPAD + koff);
      acc[0][0] = mfma16(wf2[0][ks], h0, acc[0][0]);
      acc[0][1] = mfma16(wf2[0][ks], h1, acc[0][1]);
      acc[1][0] = mfma16(wf2[1][ks], h0, acc[1][0]);
      acc[1][1] = mfma16(wf2[1][ks], h1, acc[1][1]);
    }
    // [G] epilogue: h2 = relu(acc + res); p = sum_cols h2*Wo (lane-local cols)
    float p[2] = {0.f, 0.f};
#pragma unroll
    for (int mb = 0; mb < 2; ++mb){
      const int edge = rh*32 + mb*16 + lrow;
#pragma unroll
      for (int nb = 0; nb < 2; ++nb){
        const int col0 = ch*32 + nb*16 + lk*4;
        const u16x4 rv = *(const u16x4*)(sR + edge*KPAD + col0);
#pragma unroll
        for (int r = 0; r < 4; ++r){
          float h2 = acc[nb][mb][r] + bf2f(rv[r]);
          h2 = fmaxf(h2, 0.f);
          p[mb] += h2 * wo[nb][r];
        }
      }
      p[mb] += __shfl_xor(p[mb], 16, 64);
      p[mb] += __shfl_xor(p[mb], 32, 64);
    }
    if (lk == 0){
      souts[ch][rh*32 + lrow]      = p[0];
      souts[ch][rh*32 + 16 + lrow] = p[1];
    }
    // [H] souts visible
    BARRIER();
    // [I] final combine + store
    if (t < EB){
      const int eo = tile*EB + t;
      if (eo < E)
        out[eo] = souts[0][t] + souts[1][t] + souts[2][t] + souts[3][t] + bo;
    }
    // rotate next -> cur
#pragma unroll
    for (int i = 0; i < 4; ++i){
      ctt[i] = ntt[i]; cpv[i] = npv[i]; ccv[i] = ncv[i];
    }
  }
}

// ---------------------------------------------------------------------------
// Fallback (ws too small): pure fp32, 1 wave/edge. Slow but exact.
// ---------------------------------------------------------------------------
__global__ __launch_bounds__(256) void fallback_kernel(
    const float* __restrict__ pe, const float* __restrict__ ce,
    const int* __restrict__ ei, const float* __restrict__ tte,
    const float* __restrict__ W1, const float* __restrict__ b1,
    const float* __restrict__ W2, const float* __restrict__ b2,
    const float* __restrict__ Wo, const float* __restrict__ bo,
    const float* __restrict__ Wr, const float* __restrict__ br,
    float* __restrict__ out, int E)
{
  __shared__ float sh1[4][128];
  const int w = threadIdx.x >> 6, l = threadIdx.x & 63;
  const int e_raw = blockIdx.x*4 + w;
  const int e = e_raw < E ? e_raw : E-1;
  const int s = ei[e], d = ei[E + e];
  const float tt = tte[e];
  const float* xs = pe + (size_t)s*128;
  const float* xd = ce + (size_t)d*128;
  const float x0 = xs[l], x1 = xs[64+l], x2 = xd[l], x3 = xd[64+l];
  float h1a = b1[l], h1b = b1[64+l];
  float ra = br[l], rb = br[64+l];
  for (int k = 0; k < 256; ++k){
    const float xv = (k < 64) ? x0 : (k < 128) ? x1 : (k < 192) ? x2 : x3;
    const float xk = __shfl(xv, k & 63, 64);
    h1a += xk * W1[k*128 + l];
    h1b += xk * W1[k*128 + 64 + l];
    ra  += xk * Wr[k*128 + l];
    rb  += xk * Wr[k*128 + 64 + l];
  }
  h1a += tt * W1[256*128 + l];  h1b += tt * W1[256*128 + 64 + l];
  ra  += tt * Wr[256*128 + l];  rb  += tt * Wr[256*128 + 64 + l];
  sh1[w][l] = fmaxf(h1a, 0.f);
  sh1[w][64+l] = fmaxf(h1b, 0.f);
  __syncthreads();
  float h2a = b2[l] + ra, h2b = b2[64+l] + rb;
  for (int k = 0; k < 128; ++k){
    const float hk = sh1[w][k];
    h2a += hk * W2[k*128 + l];
    h2b += hk * W2[k*128 + 64 + l];
  }
  float sum = fmaxf(h2a,0.f)*Wo[l] + fmaxf(h2b,0.f)*Wo[64+l];
  for (int off = 1; off < 64; off <<= 1) sum += __shfl_xor(sum, off, 64);
  if (l == 0 && e_raw < E) out[e_raw] = sum + bo[0];
}

extern "C" void kernel_launch(void* const* d_in, const int* in_sizes, int n_in,
                              void* d_out, int out_size, void* d_ws, size_t ws_size,
                              hipStream_t stream)
{
  const float* pe  = (const float*)d_in[0];
  const float* ce  = (const float*)d_in[1];
  const int*   ei  = (const int*)d_in[2];
  const float* tte = (const float*)d_in[3];
  const float* W1  = (const float*)d_in[4];
  const float* b1  = (const float*)d_in[5];
  const float* W2  = (const float*)d_in[6];
  const float* b2  = (const float*)d_in[7];
  const float* Wo  = (const float*)d_in[8];
  const float* bo  = (const float*)d_in[9];
  const float* Wr  = (const float*)d_in[10];
  const float* br  = (const float*)d_in[11];
  float* out = (float*)d_out;
  const int E = in_sizes[3];
  const int npat  = in_sizes[0] / 128;
  const int ncond = in_sizes[1] / 128;

  char* ws = (char*)d_ws;
  const size_t sz_PP  = (size_t)npat  * 256 * 2;
  const size_t sz_CC  = (size_t)ncond * 256 * 2;
  const size_t sz_WF  = (size_t)131072 * 2;
  const size_t sz_WF2 = (size_t)16384 * 2;
  const size_t off_PP  = 0;
  const size_t off_CC  = off_PP + sz_PP;
  const size_t off_WF  = off_CC + sz_CC;
  const size_t off_WF2 = off_WF + sz_WF;
  const size_t off_params = off_WF2 + sz_WF2;
  const size_t ws_needed = off_params + 640*4;

  if (ws_size >= ws_needed){
    u16* PP     = (u16*)(ws + off_PP);
    u16* CCb    = (u16*)(ws + off_CC);
    u16* WF     = (u16*)(ws + off_WF);
    u16* WF2    = (u16*)(ws + off_WF2);
    float* params = (float*)(ws + off_params);
    prep_kernel<<<64, 256, 0, stream>>>(W1, W2, Wo, Wr, b1, b2, br, WF, WF2, params);
    const int ptiles = (npat + 63)/64;
    mm_kernel<<<(ptiles < 1024 ? ptiles : 1024), 512, 0, stream>>>(pe, npat, ptiles, WF, nullptr, PP);
    const int ctiles = (ncond + 63)/64;
    mm_kernel<<<(ctiles < 1024 ? ctiles : 1024), 512, 0, stream>>>(ce, ncond, ctiles, WF + 65536, params + 384, CCb);
    const int etiles = (E + EB - 1)/EB;
    edge_kernel<<<(etiles < 1024 ? etiles : 1024), 512, 0, stream>>>(ei, tte, PP, CCb, WF2, params, bo, out, E, etiles);
  } else {
    fallback_kernel<<<(E + 3)/4, 256, 0, stream>>>(pe, ce, ei, tte, W1, b1, W2, b2, Wo, bo, Wr, br, out, E);
  }
}

// Round 6
// 326.277 us; speedup vs baseline: 2.9463x; 2.9463x over previous
//
#include <hip/hip_runtime.h>
#include <hip/hip_bf16.h>

using u16   = unsigned short;
using u16x4 = __attribute__((ext_vector_type(4))) unsigned short;
using u16x8 = __attribute__((ext_vector_type(8))) unsigned short;
using s16x8 = __attribute__((ext_vector_type(8))) short;
using f32x4 = __attribute__((ext_vector_type(4))) float;

#define KPAD 136   // bf16 pad stride: 272B rows -> aligned b128, low-order bank spread
#define XP   136
#define OP   264
#define EB   64

// raw barrier: LDS-visibility only, does NOT drain vmcnt -> prefetch loads stay in flight
#define BARRIER() asm volatile("s_waitcnt lgkmcnt(0)\n\ts_barrier" ::: "memory")

__device__ __forceinline__ float bf2f(u16 u){
  unsigned int x = ((unsigned int)u) << 16;
  float f; __builtin_memcpy(&f, &x, 4); return f;
}
__device__ __forceinline__ u16 f2bf(float f){
  __hip_bfloat16 h = __float2bfloat16(f);
  u16 u; __builtin_memcpy(&u, &h, 2); return u;
}
__device__ __forceinline__ f32x4 mfma16(s16x8 a, s16x8 b, f32x4 c){
  return __builtin_amdgcn_mfma_f32_16x16x32_bf16(a, b, c, 0, 0, 0);
}

// ---------------------------------------------------------------------------
// prep: WF  = layer-1 hi/lo fragment buffer [h=2][nb=16][ks=4][pair=2][lane=64][8]
//       W2T = W2^T bf16 [n=128][KPAD] (W2T[n][k] = W2[k][n])
//       params: w1t(128) | wrt(128) | Wo(128) | biasC(256)
// ---------------------------------------------------------------------------
__global__ __launch_bounds__(256) void prep_kernel(
    const float* __restrict__ W1, const float* __restrict__ W2,
    const float* __restrict__ Wo, const float* __restrict__ Wr,
    const float* __restrict__ b1, const float* __restrict__ b2,
    const float* __restrict__ br,
    u16* __restrict__ WF, u16* __restrict__ W2T, float* __restrict__ params)
{
  const int tid = blockIdx.x*256 + threadIdx.x;
  const int nth = gridDim.x*256;
  for (int id = tid; id < 131072; id += nth){
    const int j    = id & 7;
    const int lane = (id >> 3) & 63;
    const int pair = (id >> 9) & 1;
    const int ks   = (id >> 10) & 3;
    const int nb   = (id >> 12) & 15;
    const int h    = (id >> 16) & 1;
    const int k = ks*32 + (lane >> 4)*8 + j;
    const int n = nb*16 + (lane & 15);
    const float v = ((n < 128) ? W1 : Wr)[(h*128 + k)*128 + (n & 127)];
    const u16 hi = f2bf(v);
    WF[id] = pair ? f2bf(v - bf2f(hi)) : hi;
  }
  for (int id = tid; id < 128*128; id += nth){
    const int k = id >> 7, n = id & 127;
    W2T[n*KPAD + k] = f2bf(W2[k*128 + n]);
  }
  for (int id = tid; id < 128; id += nth){
    params[id]       = W1[256*128 + id];      // w1t
    params[128 + id] = Wr[256*128 + id];      // wrt
    params[256 + id] = Wo[id];                // Wo
    params[384 + id]       = b1[id];          // biasC 0..127
    params[384 + 128 + id] = br[id] + b2[id]; // biasC 128..255
  }
}

// ---------------------------------------------------------------------------
// mm: out[row][0..255] = emb[row] @ Wcat (+bias), split-bf16 3-MFMA.
// 512 thr = 8 waves, 64-row tiles, W frags register-stationary (wave w owns
// cols w*16 and (w+8)*16). launch_bounds (512,4): VGPR cap 128, no spills.
// ---------------------------------------------------------------------------
__global__ __launch_bounds__(512, 4) void mm_kernel(
    const float* __restrict__ emb, int nrows, int ntiles,
    const u16* __restrict__ WFh, const float* __restrict__ bias,
    u16* __restrict__ outbuf)
{
  __shared__ __align__(16) char smem_raw[64*XP*2*2];   // 34816 B
  u16* xhi = (u16*)smem_raw;              // [64][XP]
  u16* xlo = xhi + 64*XP;
  u16* sO  = (u16*)smem_raw;              // aliased after compute: [64][OP]
  const int t = threadIdx.x;
  const int l = t & 63, w = t >> 6;       // w in [0,8)
  const int lrow = l & 15, lq = l >> 4;
  s16x8 wf[2][4][2];                      // [nbh][ks][hi/lo]
#pragma unroll
  for (int nbh = 0; nbh < 2; ++nbh)
#pragma unroll
    for (int ks = 0; ks < 4; ++ks){
      const int nb = w + nbh*8;
      const u16* base = WFh + (size_t)((nb*4 + ks)*2)*512 + l*8;
      wf[nbh][ks][0] = *(const s16x8*)(base);
      wf[nbh][ks][1] = *(const s16x8*)(base + 512);
    }
  float bv[2][4] = {{0.f,0.f,0.f,0.f},{0.f,0.f,0.f,0.f}};
  if (bias){
#pragma unroll
    for (int nbh = 0; nbh < 2; ++nbh)
#pragma unroll
      for (int r = 0; r < 4; ++r)
        bv[nbh][r] = bias[(w + nbh*8)*16 + lq*4 + r];
  }
  for (int tile = blockIdx.x; tile < ntiles; tile += gridDim.x){
    const int row0 = tile*64;
    BARRIER();   // prev tile's sO fully consumed
#pragma unroll
    for (int i = 0; i < 4; ++i){
      const int f4 = i*512 + t;
      const int r = f4 >> 5, kc = f4 & 31;
      int grow = row0 + r; if (grow >= nrows) grow = nrows - 1;
      const float4 v = *(const float4*)(emb + (size_t)grow*128 + kc*4);
      const float vv[4] = {v.x, v.y, v.z, v.w};
      u16x4 h4, l4;
#pragma unroll
      for (int q = 0; q < 4; ++q){
        const u16 hi = f2bf(vv[q]);
        h4[q] = hi;
        l4[q] = f2bf(vv[q] - bf2f(hi));
      }
      *(u16x4*)(xhi + r*XP + kc*4) = h4;
      *(u16x4*)(xlo + r*XP + kc*4) = l4;
    }
    BARRIER();
    f32x4 acc[2][4];                      // [nbh][mb]
#pragma unroll
    for (int a = 0; a < 2; ++a)
#pragma unroll
      for (int b = 0; b < 4; ++b) acc[a][b] = (f32x4){0.f,0.f,0.f,0.f};
#pragma unroll
    for (int mb = 0; mb < 4; ++mb){
      const int mro = (mb*16 + lrow)*XP + lq*8;
#pragma unroll
      for (int ks = 0; ks < 4; ++ks){
        const s16x8 xh = *(const s16x8*)(xhi + mro + ks*32);
        const s16x8 xl = *(const s16x8*)(xlo + mro + ks*32);
#pragma unroll
        for (int nbh = 0; nbh < 2; ++nbh){
          acc[nbh][mb] = mfma16(wf[nbh][ks][0], xh, acc[nbh][mb]);
          acc[nbh][mb] = mfma16(wf[nbh][ks][1], xh, acc[nbh][mb]);
          acc[nbh][mb] = mfma16(wf[nbh][ks][0], xl, acc[nbh][mb]);
        }
      }
    }
    BARRIER();   // x consumed -> alias LDS as sO
#pragma unroll
    for (int nbh = 0; nbh < 2; ++nbh)
#pragma unroll
      for (int mb = 0; mb < 4; ++mb){
        const int m = mb*16 + lrow;
        u16x4 o;
#pragma unroll
        for (int r = 0; r < 4; ++r) o[r] = f2bf(acc[nbh][mb][r] + bv[nbh][r]);
        *(u16x4*)(sO + m*OP + (w + nbh*8)*16 + lq*4) = o;
      }
    BARRIER();
#pragma unroll
    for (int i = 0; i < 4; ++i){
      const int idx = i*512 + t;
      const int m = idx >> 5, c = idx & 31;
      const int grow = row0 + m;
      if (grow < nrows){
        const u16x8 v = *(const u16x8*)(sO + m*OP + c*8);
        *(u16x8*)(outbuf + (size_t)grow*256 + c*8) = v;
      }
    }
  }
}

// ---------------------------------------------------------------------------
// Edge kernel: 512 thr (8 waves), 64 edges/tile. W2 in LDS (frees VGPRs for
// the gather pipeline: cur+next payload in regs, raw lgkm-only barriers keep
// next-tile gathers in flight under MFMA+epilogue). (512,4): no spills.
// Swapped-operand MFMA: D = [out-col][edge] -> lane-local vectorized epilogue.
// ---------------------------------------------------------------------------
__global__ __launch_bounds__(512, 4) void edge_kernel(
    const int* __restrict__ ei, const float* __restrict__ tte,
    const u16* __restrict__ PP, const u16* __restrict__ CC,
    const u16* __restrict__ W2T, const float* __restrict__ params,
    const float* __restrict__ bo_p, float* __restrict__ out, int E, int ntiles)
{
  __shared__ u16 sW2T[128*KPAD];   // 34816 B
  __shared__ u16 sA[EB*KPAD];      // h1  bf16 [64][136]
  __shared__ u16 sR[EB*KPAD];      // res bf16 [64][136]
  __shared__ float sw1t[128], swrt[128], sWo[128];
  __shared__ float souts[4][EB];
  const int t = threadIdx.x;
  const int l = t & 63, w = t >> 6;
  const int lrow = l & 15, lk = l >> 4;
  const int rh = w & 1, ch = w >> 1;     // edge-half(32), col-quarter(32)
  const int gid = t >> 5, gl = t & 31;   // gather group(16 edges) / chunk
  const float bo = bo_p[0];
  {
    const u16x8* g = (const u16x8*)W2T;
    u16x8* s = (u16x8*)sW2T;
    for (int i = t; i < 128*KPAD/8; i += 512) s[i] = g[i];
  }
  if (t < 128){ sw1t[t] = params[t]; swrt[t] = params[128+t]; sWo[t] = params[256+t]; }

  int tile = blockIdx.x;
  if (tile >= ntiles) return;
  // prologue: indices + gathers for first tile
  float ctt[4];
  u16x8 cpv[4], ccv[4];
  {
    int cs[4], cd[4];
#pragma unroll
    for (int i = 0; i < 4; ++i){
      int e = tile*EB + i*16 + gid; if (e >= E) e = E - 1;
      cs[i] = ei[e]; cd[i] = ei[E + e]; ctt[i] = tte[e];
    }
#pragma unroll
    for (int i = 0; i < 4; ++i){
      cpv[i] = *(const u16x8*)(PP + (size_t)cs[i]*256 + gl*8);
      ccv[i] = *(const u16x8*)(CC + (size_t)cd[i]*256 + gl*8);
    }
  }
  BARRIER();   // sW2T / sw1t etc ready (first pass)

  for (; tile < ntiles; tile += gridDim.x){
    const int ntile = tile + gridDim.x;
    // [C] convert current gathers -> sA/sR
#pragma unroll
    for (int i = 0; i < 4; ++i){
      const int e = i*16 + gid;
      const int jj = (gl & 15)*8;
      const float tt = ctt[i];
      const float* wt = (gl < 16) ? (sw1t + jj) : (swrt + jj);
      u16x8 o;
#pragma unroll
      for (int q = 0; q < 8; ++q){
        float v = bf2f(cpv[i][q]) + bf2f(ccv[i][q]) + tt * wt[q];
        if (gl < 16) v = fmaxf(v, 0.f);
        o[q] = f2bf(v);
      }
      u16* dst = (gl < 16) ? (sA + e*KPAD + jj) : (sR + e*KPAD + jj);
      *(u16x8*)dst = o;
    }
    // [D] next-tile indices + gathers -- stay in flight across the raw barrier
    u16x8 npv[4], ncv[4];
    float ntt[4];
    {
      int nxs[4], nxd[4];
#pragma unroll
      for (int i = 0; i < 4; ++i){
        int e = ntile*EB + i*16 + gid; if (e >= E) e = E - 1;
        nxs[i] = ei[e]; nxd[i] = ei[E + e]; ntt[i] = tte[e];
      }
#pragma unroll
      for (int i = 0; i < 4; ++i){
        npv[i] = *(const u16x8*)(PP + (size_t)nxs[i]*256 + gl*8);
        ncv[i] = *(const u16x8*)(CC + (size_t)nxd[i]*256 + gl*8);
      }
    }
    // [E] sA/sR visible
    BARRIER();
    // [F] MFMA: acc[nb][mb]; A = W2 frag from LDS, B = h1 frag from LDS
    f32x4 acc[2][2];
#pragma unroll
    for (int a = 0; a < 2; ++a)
#pragma unroll
      for (int b = 0; b < 2; ++b) acc[a][b] = (f32x4){0.f,0.f,0.f,0.f};
#pragma unroll
    for (int ks = 0; ks < 4; ++ks){
      const int koff = ks*32 + lk*8;
      const s16x8 h0 = *(const s16x8*)(sA + (rh*32 + lrow)*KPAD + koff);
      const s16x8 h1 = *(const s16x8*)(sA + (rh*32 + 16 + lrow)*KPAD + koff);
      const s16x8 b0 = *(const s16x8*)(sW2T + (ch*32 + lrow)*KPAD + koff);
      const s16x8 b1 = *(const s16x8*)(sW2T + (ch*32 + 16 + lrow)*KPAD + koff);
      acc[0][0] = mfma16(b0, h0, acc[0][0]);
      acc[0][1] = mfma16(b0, h1, acc[0][1]);
      acc[1][0] = mfma16(b1, h0, acc[1][0]);
      acc[1][1] = mfma16(b1, h1, acc[1][1]);
    }
    // [G] epilogue: h2 = relu(acc + res); p = sum over lane-local cols of h2*Wo
    float p[2] = {0.f, 0.f};
    float wo[2][4];
#pragma unroll
    for (int nb = 0; nb < 2; ++nb){
#pragma unroll
      for (int r = 0; r < 4; ++r) wo[nb][r] = sWo[ch*32 + nb*16 + lk*4 + r];
    }
#pragma unroll
    for (int mb = 0; mb < 2; ++mb){
      const int edge = rh*32 + mb*16 + lrow;
#pragma unroll
      for (int nb = 0; nb < 2; ++nb){
        const int col0 = ch*32 + nb*16 + lk*4;
        const u16x4 rv = *(const u16x4*)(sR + edge*KPAD + col0);
#pragma unroll
        for (int r = 0; r < 4; ++r){
          float h2 = acc[nb][mb][r] + bf2f(rv[r]);
          h2 = fmaxf(h2, 0.f);
          p[mb] += h2 * wo[nb][r];
        }
      }
      p[mb] += __shfl_xor(p[mb], 16, 64);
      p[mb] += __shfl_xor(p[mb], 32, 64);
    }
    if (lk == 0){
      souts[ch][rh*32 + lrow]      = p[0];
      souts[ch][rh*32 + 16 + lrow] = p[1];
    }
    // [H] souts visible
    BARRIER();
    // [I] final combine + store
    if (t < EB){
      const int eo = tile*EB + t;
      if (eo < E)
        out[eo] = souts[0][t] + souts[1][t] + souts[2][t] + souts[3][t] + bo;
    }
    // [B] sA/sR consumed; next iter's [C] may overwrite
    BARRIER();
    // rotate next -> cur
#pragma unroll
    for (int i = 0; i < 4; ++i){
      ctt[i] = ntt[i]; cpv[i] = npv[i]; ccv[i] = ncv[i];
    }
  }
}

// ---------------------------------------------------------------------------
// Fallback (ws too small): pure fp32, 1 wave/edge. Slow but exact.
// ---------------------------------------------------------------------------
__global__ __launch_bounds__(256) void fallback_kernel(
    const float* __restrict__ pe, const float* __restrict__ ce,
    const int* __restrict__ ei, const float* __restrict__ tte,
    const float* __restrict__ W1, const float* __restrict__ b1,
    const float* __restrict__ W2, const float* __restrict__ b2,
    const float* __restrict__ Wo, const float* __restrict__ bo,
    const float* __restrict__ Wr, const float* __restrict__ br,
    float* __restrict__ out, int E)
{
  __shared__ float sh1[4][128];
  const int w = threadIdx.x >> 6, l = threadIdx.x & 63;
  const int e_raw = blockIdx.x*4 + w;
  const int e = e_raw < E ? e_raw : E-1;
  const int s = ei[e], d = ei[E + e];
  const float tt = tte[e];
  const float* xs = pe + (size_t)s*128;
  const float* xd = ce + (size_t)d*128;
  const float x0 = xs[l], x1 = xs[64+l], x2 = xd[l], x3 = xd[64+l];
  float h1a = b1[l], h1b = b1[64+l];
  float ra = br[l], rb = br[64+l];
  for (int k = 0; k < 256; ++k){
    const float xv = (k < 64) ? x0 : (k < 128) ? x1 : (k < 192) ? x2 : x3;
    const float xk = __shfl(xv, k & 63, 64);
    h1a += xk * W1[k*128 + l];
    h1b += xk * W1[k*128 + 64 + l];
    ra  += xk * Wr[k*128 + l];
    rb  += xk * Wr[k*128 + 64 + l];
  }
  h1a += tt * W1[256*128 + l];  h1b += tt * W1[256*128 + 64 + l];
  ra  += tt * Wr[256*128 + l];  rb  += tt * Wr[256*128 + 64 + l];
  sh1[w][l] = fmaxf(h1a, 0.f);
  sh1[w][64+l] = fmaxf(h1b, 0.f);
  __syncthreads();
  float h2a = b2[l] + ra, h2b = b2[64+l] + rb;
  for (int k = 0; k < 128; ++k){
    const float hk = sh1[w][k];
    h2a += hk * W2[k*128 + l];
    h2b += hk * W2[k*128 + 64 + l];
  }
  float sum = fmaxf(h2a,0.f)*Wo[l] + fmaxf(h2b,0.f)*Wo[64+l];
  for (int off = 1; off < 64; off <<= 1) sum += __shfl_xor(sum, off, 64);
  if (l == 0 && e_raw < E) out[e_raw] = sum + bo[0];
}

extern "C" void kernel_launch(void* const* d_in, const int* in_sizes, int n_in,
                              void* d_out, int out_size, void* d_ws, size_t ws_size,
                              hipStream_t stream)
{
  const float* pe  = (const float*)d_in[0];
  const float* ce  = (const float*)d_in[1];
  const int*   ei  = (const int*)d_in[2];
  const float* tte = (const float*)d_in[3];
  const float* W1  = (const float*)d_in[4];
  const float* b1  = (const float*)d_in[5];
  const float* W2  = (const float*)d_in[6];
  const float* b2  = (const float*)d_in[7];
  const float* Wo  = (const float*)d_in[8];
  const float* bo  = (const float*)d_in[9];
  const float* Wr  = (const float*)d_in[10];
  const float* br  = (const float*)d_in[11];
  float* out = (float*)d_out;
  const int E = in_sizes[3];
  const int npat  = in_sizes[0] / 128;
  const int ncond = in_sizes[1] / 128;

  char* ws = (char*)d_ws;
  const size_t sz_PP  = (size_t)npat  * 256 * 2;
  const size_t sz_CC  = (size_t)ncond * 256 * 2;
  const size_t sz_WF  = (size_t)131072 * 2;
  const size_t sz_W2T = (size_t)128 * KPAD * 2;
  const size_t off_PP  = 0;
  const size_t off_CC  = off_PP + sz_PP;
  const size_t off_WF  = off_CC + sz_CC;
  const size_t off_W2T = off_WF + sz_WF;
  const size_t off_params = off_W2T + sz_W2T;
  const size_t ws_needed = off_params + 640*4;

  if (ws_size >= ws_needed){
    u16* PP     = (u16*)(ws + off_PP);
    u16* CCb    = (u16*)(ws + off_CC);
    u16* WF     = (u16*)(ws + off_WF);
    u16* W2T    = (u16*)(ws + off_W2T);
    float* params = (float*)(ws + off_params);
    prep_kernel<<<64, 256, 0, stream>>>(W1, W2, Wo, Wr, b1, b2, br, WF, W2T, params);
    const int ptiles = (npat + 63)/64;
    mm_kernel<<<(ptiles < 512 ? ptiles : 512), 512, 0, stream>>>(pe, npat, ptiles, WF, nullptr, PP);
    const int ctiles = (ncond + 63)/64;
    mm_kernel<<<(ctiles < 512 ? ctiles : 512), 512, 0, stream>>>(ce, ncond, ctiles, WF + 65536, params + 384, CCb);
    const int etiles = (E + EB - 1)/EB;
    edge_kernel<<<(etiles < 512 ? etiles : 512), 512, 0, stream>>>(ei, tte, PP, CCb, W2T, params, bo, out, E, etiles);
  } else {
    fallback_kernel<<<(E + 3)/4, 256, 0, stream>>>(pe, ce, ei, tte, W1, b1, W2, b2, Wo, bo, Wr, br, out, E);
  }
}